// Round 13
// baseline (181.041 us; speedup 1.0000x reference)
//
#include <hip/hip_runtime.h>
#include <hip/hip_fp16.h>

typedef unsigned int u32;
typedef unsigned short u16;
typedef __attribute__((ext_vector_type(8))) _Float16 f16x8;
typedef __attribute__((ext_vector_type(4))) float f32x4;
typedef __attribute__((ext_vector_type(4))) u32 u32x4;

#define M_DIM 256
#define K_DIM 4096
#define N_DIM 14336
#define NBLK 896            // 4 kq * 224 nt ; 4 waves/block = 4 mt

union U4F8 { u32x4 u; f16x8 v; };

// dequant one int32 (8 nibbles, sigma k-order [0,4,1,5,2,6,3,7]) -> f16x8
// w = RN( RN(s*q) - z ): d2 = -1024*s EXACT in f16 -> bit-identical to ref.
__device__ __forceinline__ f16x8 dq8(u32 q, __half2 s2, __half2 d2, __half2 z2) {
  const u32 q1 = q >> 4, q2 = q >> 8, q3 = q >> 12;
  U4F8 r;
  const u32 x0 = ( q & 0x000F000Fu) | 0x64006400u;   // {1024+n_j, 1024+n_{j+4}}
  const u32 x1 = (q1 & 0x000F000Fu) | 0x64006400u;
  const u32 x2 = (q2 & 0x000F000Fu) | 0x64006400u;
  const u32 x3 = (q3 & 0x000F000Fu) | 0x64006400u;
  r.u.x = __builtin_bit_cast(u32, __hsub2(__hfma2(__builtin_bit_cast(__half2, x0), s2, d2), z2));
  r.u.y = __builtin_bit_cast(u32, __hsub2(__hfma2(__builtin_bit_cast(__half2, x1), s2, d2), z2));
  r.u.z = __builtin_bit_cast(u32, __hsub2(__hfma2(__builtin_bit_cast(__half2, x2), s2, d2), z2));
  r.u.w = __builtin_bit_cast(u32, __hsub2(__hfma2(__builtin_bit_cast(__half2, x3), s2, d2), z2));
  return r.v;
}

__device__ __forceinline__ u32 pkrtz(float a, float b) {  // exact: x was f16
  return __builtin_bit_cast(u32, __builtin_amdgcn_cvt_pkrtz(a, b));
}

// prep: blocks 0..511 convert X f32 -> sigma-packed f16 in ws; 512..4095 zero O
__global__ __launch_bounds__(256) void prep(const float* __restrict__ X,
                                            u16* __restrict__ Xh,
                                            float* __restrict__ O) {
  const int b = blockIdx.x;
  if (b < 512) {
    const int g = b * 256 + threadIdx.x;          // 131072 chunks of 8
    const float* p = X + (size_t)g * 8;
    const f32x4 lo = *(const f32x4*)p;
    const f32x4 hi = *(const f32x4*)(p + 4);
    u32x4 pk;                                     // sigma: pairs (c, c+4)
    pk.x = pkrtz(lo.x, hi.x);
    pk.y = pkrtz(lo.y, hi.y);
    pk.z = pkrtz(lo.z, hi.z);
    pk.w = pkrtz(lo.w, hi.w);
    *(u32x4*)(Xh + (size_t)g * 8) = pk;
  } else {
    const size_t i = (size_t)(b - 512) * 256 + threadIdx.x;  // 3584*256*4 f32 exact
    ((f32x4*)O)[i] = (f32x4){0.f, 0.f, 0.f, 0.f};
  }
}

__global__ __launch_bounds__(256, 3) void kivi_gemm(
    const u16* __restrict__ Xh,     // sigma-packed f16 x [256][4096] (in ws)
    const int* __restrict__ QW,     // [512][14336]; nibble j of row r -> k = r*8+j
    const float* __restrict__ S,    // [32][14336]
    const float* __restrict__ Z,    // [32][14336]
    float* __restrict__ O)          // out f32 [256][14336], pre-zeroed
{
  const int tid  = threadIdx.x;
  const int lane = tid & 63;
  const int mt   = tid >> 6;        // 4 independent waves: m-bands (no barriers!)

  // XCD swizzle: 896 = 8*112; XCD x gets one kq-slice of 112 consecutive nt
  // -> QW slice 3.7 MB (L2-resident across its 4 mt readers), Xh slice 0.5 MB
  const int b  = blockIdx.x;
  const int L  = (b & 7) * 112 + (b >> 3);
  const int kq = L / 224;           // 0..3 k-quarter (waves share kq, nt)
  const int nt = L % 224;           // 0..223
  const int n0 = nt * 64;

  const int fr = lane & 15, fq = lane >> 4;
  const int cb = n0 + fr;                       // B col (ni -> +16*ni)
  const u16* aBase = Xh + (size_t)(mt * 64 + fr) * K_DIM + kq * 1024 + fq * 8;
  const int* qBase = QW + (size_t)(kq * 128 + fq) * N_DIM + cb;

  f32x4 acc[4][4];
#pragma unroll
  for (int mi = 0; mi < 4; ++mi)
#pragma unroll
    for (int ni = 0; ni < 4; ++ni)
      acc[mi][ni] = (f32x4){0.f, 0.f, 0.f, 0.f};

  f16x8 a0[4], a1[4];               // A depth-2 (L2, ~200 cyc)
  u32 q0[4], q1[4], q2[4], q3[4];   // B depth-4 (HBM, ~900 cyc)
  float sv[4], zv[4];
  __half2 sh2[4], dh2[4], zh2[4];

  auto loadA = [&](int i, f16x8 (&a)[4]) {
#pragma unroll
    for (int mi = 0; mi < 4; ++mi)
      a[mi] = *(const f16x8*)(aBase + (size_t)mi * 16 * K_DIM + i * 32);
  };
  auto loadB = [&](int i, u32 (&q)[4]) {
#pragma unroll
    for (int ni = 0; ni < 4; ++ni)
      q[ni] = *(const u32*)(qBase + (size_t)i * 4 * N_DIM + ni * 16);
  };
  auto loadS = [&](int i) {
    const int g = kq * 8 + (i >> 2);            // GROUP=128 = 4 K-steps
#pragma unroll
    for (int ni = 0; ni < 4; ++ni) {
      sv[ni] = S[(size_t)g * N_DIM + cb + ni * 16];
      zv[ni] = Z[(size_t)g * N_DIM + cb + ni * 16];
    }
  };
  auto mkconsts = [&]() {
    const __half hneg1024 = __float2half(-1024.f);
#pragma unroll
    for (int ni = 0; ni < 4; ++ni) {
      const __half sh = __float2half(sv[ni]);   // matches ref astype(f16)
      const __half zh = __float2half(zv[ni]);
      const __half dh = __hmul(sh, hneg1024);   // exact: exponent shift
      sh2[ni] = __halves2half2(sh, sh);
      dh2[ni] = __halves2half2(dh, dh);
      zh2[ni] = __halves2half2(zh, zh);
    }
  };
  auto compute = [&](const f16x8 (&a)[4], const u32 (&q)[4]) {
    f16x8 bf[4];
#pragma unroll
    for (int ni = 0; ni < 4; ++ni)
      bf[ni] = dq8(q[ni], sh2[ni], dh2[ni], zh2[ni]);
    __builtin_amdgcn_s_setprio(1);
#pragma unroll
    for (int mi = 0; mi < 4; ++mi)
#pragma unroll
      for (int ni = 0; ni < 4; ++ni)
        acc[mi][ni] = __builtin_amdgcn_mfma_f32_16x16x32_f16(
            a[mi], bf[ni], acc[mi][ni], 0, 0, 0);
    __builtin_amdgcn_s_setprio(0);
  };

  // prologue: scales g0; A depth-2; B depth-4
  loadS(0);
  loadA(0, a0); loadA(1, a1);
  loadB(0, q0); loadB(1, q1); loadB(2, q2); loadB(3, q3);

#pragma unroll 1
  for (int i = 0; i < 32; i += 4) {           // one quad = one scale group
    mkconsts();
    compute(a0, q0);
    if (i + 2 < 32) loadA(i + 2, a0);
    if (i + 4 < 32) loadB(i + 4, q0);
    __builtin_amdgcn_sched_barrier(0);
    compute(a1, q1);
    if (i + 3 < 32) loadA(i + 3, a1);
    if (i + 5 < 32) loadB(i + 5, q1);
    if (i + 4 < 32) loadS(i + 4);             // scales half-a-quad ahead
    __builtin_amdgcn_sched_barrier(0);
    compute(a0, q2);
    if (i + 4 < 32) loadA(i + 4, a0);
    if (i + 6 < 32) loadB(i + 6, q2);
    __builtin_amdgcn_sched_barrier(0);
    compute(a1, q3);
    if (i + 5 < 32) loadA(i + 5, a1);
    if (i + 7 < 32) loadB(i + 7, q3);
    __builtin_amdgcn_sched_barrier(0);
  }

  // epilogue: k-quarter partials -> hardware f32 atomics (4 addends/output)
#pragma unroll
  for (int mi = 0; mi < 4; ++mi)
#pragma unroll
    for (int ni = 0; ni < 4; ++ni)
#pragma unroll
      for (int r = 0; r < 4; ++r) {
        const int row = mt * 64 + mi * 16 + fq * 4 + r;
        const int col = n0 + ni * 16 + fr;
        unsafeAtomicAdd(&O[(size_t)row * N_DIM + col], acc[mi][ni][r]);
      }
}

extern "C" void kernel_launch(void* const* d_in, const int* in_sizes, int n_in,
                              void* d_out, int out_size, void* d_ws, size_t ws_size,
                              hipStream_t stream) {
  const float* X  = (const float*)d_in[0];
  const int*   QW = (const int*)d_in[1];
  const float* S  = (const float*)d_in[2];
  const float* Zp = (const float*)d_in[3];
  float* O  = (float*)d_out;
  u16*   Xh = (u16*)d_ws;                      // 2 MB sigma-packed f16 x
  hipLaunchKernelGGL(prep, dim3(4096), dim3(256), 0, stream, X, Xh, O);
  hipLaunchKernelGGL(kivi_gemm, dim3(NBLK), dim3(256), 0, stream, Xh, QW, S, Zp, O);
}